// Round 1
// baseline (20044.759 us; speedup 1.0000x reference)
//
#include <hip/hip_runtime.h>
#include <hip/hip_bf16.h>

#define SEQ  512
#define BATCH 64
#define HID  1024
#define G4   4096
#define NBLK 128

typedef short bf16x8 __attribute__((ext_vector_type(8)));
typedef float f32x4  __attribute__((ext_vector_type(4)));

static __device__ __forceinline__ unsigned short f2b(float f) {
  union { float f; unsigned u; } v; v.f = f;
  unsigned r = (v.u + 0x7FFFu + ((v.u >> 16) & 1u)) >> 16;  // RNE
  return (unsigned short)r;
}

// x (B,S,I) f32 -> xb row-major (S*B, I) bf16, row r = s*64+b
__global__ __launch_bounds__(256) void k_castx(const float* __restrict__ x,
                                               unsigned short* __restrict__ xb) {
  int idx = blockIdx.x * 256 + threadIdx.x;   // 8,388,608 threads
  int r = idx >> 8, kq = idx & 255;
  int b = r & 63, s = r >> 6;
  float4 v = *reinterpret_cast<const float4*>(x + ((size_t)b * SEQ + s) * HID + (size_t)kq * 4);
  ushort4 o;
  o.x = f2b(v.x); o.y = f2b(v.y); o.z = f2b(v.z); o.w = f2b(v.w);
  *reinterpret_cast<ushort4*>(xb + (size_t)r * HID + kq * 4) = o;
}

// W (K=1024, N=4096) f32 -> WT (N=4096, K=1024) bf16
__global__ __launch_bounds__(256) void k_wtrans(const float* __restrict__ W,
                                                unsigned short* __restrict__ WT) {
  __shared__ float tls[32][33];
  int tile = blockIdx.x;               // 32 k-tiles x 128 n-tiles
  int nt = tile & 127, kt = tile >> 7;
  int tx = threadIdx.x & 31, ty = threadIdx.x >> 5;
  int k0 = kt * 32, n0 = nt * 32;
  for (int i = 0; i < 4; ++i)
    tls[ty + 8 * i][tx] = W[(size_t)(k0 + ty + 8 * i) * G4 + n0 + tx];
  __syncthreads();
  for (int i = 0; i < 4; ++i)
    WT[(size_t)(n0 + ty + 8 * i) * HID + k0 + tx] = f2b(tls[tx][ty + 8 * i]);
}

// Persistent fused LSTM layer scan.
// aseq: (S*B, 1024) bf16 input rows. WxT/WhT: (4096,1024) bf16. bias: f32[4096].
// hbuf: ring of ring_mod slots of (64,1024) bf16. fout: (B,S,H) f32 or null.
__global__ __launch_bounds__(256, 1) void k_scan(
    const unsigned short* __restrict__ aseq,
    const unsigned short* __restrict__ WxT,
    const unsigned short* __restrict__ WhT,
    const float* __restrict__ bias,
    unsigned short* __restrict__ hbuf, int ring_mod,
    float* __restrict__ fout,
    unsigned* __restrict__ bar) {
  __shared__ unsigned short wlds[32 * 2048];  // 128KB, [c][k] swizzled
  __shared__ float glds[64][36];

  const int bk  = blockIdx.x;
  const int tid = threadIdx.x;
  const int w   = tid >> 6;
  const int l   = tid & 63;
  const int lq  = l >> 4, lr = l & 15;

  // ---- one-time: stage weight slice into LDS (swizzled byte addr) ----
  {
    int c = tid >> 3, seg = tid & 7;
    int gate = c >> 3, nl = c & 7;
    int gcol = gate * 1024 + bk * 8 + nl;
    const unsigned short* sx = WxT + (size_t)gcol * HID;
    const unsigned short* sh = WhT + (size_t)gcol * HID;
    for (int j = 0; j < 32; ++j) {
      int kk = seg * 256 + j * 8;   // element index in [0,2048)
      const unsigned short* src = (kk < 1024) ? (sx + kk) : (sh + (kk - 1024));
      uint4 v = *reinterpret_cast<const uint4*>(src);
      int db = (c * 4096 + kk * 2) ^ ((c & 7) << 4);
      *reinterpret_cast<uint4*>(reinterpret_cast<char*>(wlds) + db) = v;
    }
  }
  __syncthreads();

  // elementwise role constants
  const int nl_e = tid & 7, brow = tid >> 3;       // brow 0..31 -> b, b+32
  const int col_e = bk * 8 + nl_e;
  const float bi = bias[col_e];
  const float bfv = bias[1024 + col_e];
  const float bg = bias[2048 + col_e];
  const float bo = bias[3072 + col_e];
  float cA = 0.f, cB = 0.f;

  // MFMA role constants
  const int arow = w * 16 + lr;                     // batch row 0..63
  const int csw = (lr & 7) << 4;                    // swizzle bits
  const int cb0 = (0 * 16 + lr) * 4096 + lq * 16;   // nt=0 base (linear)
  const int cb1 = (16 + lr) * 4096 + lq * 16;       // nt=1 base (linear)
  char* wbase = reinterpret_cast<char*>(wlds);

  unsigned epoch = 0;

  for (int t = 0; t < SEQ; ++t) {
    f32x4 acc[2][2] = {};   // [ntile][ks parity]

    // ---- x_t @ Wx part (K 0..1023) ----
    {
      const unsigned short* ax = aseq + ((size_t)t * 64 + arow) * HID + lq * 8;
#pragma unroll 8
      for (int ks = 0; ks < 32; ++ks) {
        bf16x8 a = *reinterpret_cast<const bf16x8*>(ax + ks * 32);
        bf16x8 b0 = *reinterpret_cast<const bf16x8*>(wbase + ((cb0 + ks * 64) ^ csw));
        bf16x8 b1 = *reinterpret_cast<const bf16x8*>(wbase + ((cb1 + ks * 64) ^ csw));
        acc[0][ks & 1] = __builtin_amdgcn_mfma_f32_16x16x32_bf16(a, b0, acc[0][ks & 1], 0, 0, 0);
        acc[1][ks & 1] = __builtin_amdgcn_mfma_f32_16x16x32_bf16(a, b1, acc[1][ks & 1], 0, 0, 0);
      }
    }
    // ---- h_{t-1} @ Wh part (K 1024..2047); h_{-1} = 0 -> skip ----
    if (t > 0) {
      const unsigned short* ah = hbuf + (size_t)((t - 1) % ring_mod) * (64 * HID)
                                 + (size_t)arow * HID + lq * 8;
#pragma unroll 8
      for (int ks = 0; ks < 32; ++ks) {
        bf16x8 a = *reinterpret_cast<const bf16x8*>(ah + ks * 32);
        bf16x8 b0 = *reinterpret_cast<const bf16x8*>(wbase + ((cb0 + 2048 + ks * 64) ^ csw));
        bf16x8 b1 = *reinterpret_cast<const bf16x8*>(wbase + ((cb1 + 2048 + ks * 64) ^ csw));
        acc[0][ks & 1] = __builtin_amdgcn_mfma_f32_16x16x32_bf16(a, b0, acc[0][ks & 1], 0, 0, 0);
        acc[1][ks & 1] = __builtin_amdgcn_mfma_f32_16x16x32_bf16(a, b1, acc[1][ks & 1], 0, 0, 0);
      }
    }

    // ---- dump g to LDS: row = w*16 + lq*4 + r, col = nt*16 + lr ----
#pragma unroll
    for (int nt = 0; nt < 2; ++nt) {
      f32x4 s = acc[nt][0] + acc[nt][1];
      int row = w * 16 + lq * 4;
      int col = nt * 16 + lr;
      glds[row + 0][col] = s.x;
      glds[row + 1][col] = s.y;
      glds[row + 2][col] = s.z;
      glds[row + 3][col] = s.w;
    }
    __syncthreads();

    // ---- gates + state update: thread handles (brow, nl_e) and (brow+32, nl_e) ----
    {
      unsigned short* hw = hbuf + (size_t)(t % ring_mod) * (64 * HID);
#pragma unroll
      for (int half = 0; half < 2; ++half) {
        int b = brow + half * 32;
        float& cst = half ? cB : cA;
        float gi = glds[b][nl_e] + bi;
        float gf = glds[b][8 + nl_e] + bfv;
        float gg = glds[b][16 + nl_e] + bg;
        float go = glds[b][24 + nl_e] + bo;
        float ig = 1.f / (1.f + __expf(-gi));
        float fg = 1.f / (1.f + __expf(-gf));
        float e2 = __expf(2.f * gg);
        float gv = (e2 - 1.f) / (e2 + 1.f);
        float og = 1.f / (1.f + __expf(-go));
        cst = fg * cst + ig * gv;
        float e2c = __expf(2.f * cst);
        float th = (e2c - 1.f) / (e2c + 1.f);
        float h = og * th;
        hw[(size_t)b * HID + col_e] = f2b(h);
        if (fout) fout[(size_t)b * (SEQ * HID) + (size_t)t * HID + col_e] = h;
      }
    }

    // ---- grid barrier (release h writes, acquire for next step) ----
    if (t != SEQ - 1) {
      __syncthreads();
      if (tid == 0) {
        __threadfence();
        __hip_atomic_fetch_add(bar, 1u, __ATOMIC_RELEASE, __HIP_MEMORY_SCOPE_AGENT);
        ++epoch;
        unsigned target = epoch * NBLK;
        long spins = 0;
        while (__hip_atomic_load(bar, __ATOMIC_RELAXED, __HIP_MEMORY_SCOPE_AGENT) < target) {
          if (++spins > 30000000L) break;  // bailout: wrong answer beats a hang
          __builtin_amdgcn_s_sleep(2);
        }
      }
      __syncthreads();
      __builtin_amdgcn_fence(__ATOMIC_ACQUIRE, "agent");
    }
  }
}

extern "C" void kernel_launch(void* const* d_in, const int* in_sizes, int n_in,
                              void* d_out, int out_size, void* d_ws, size_t ws_size,
                              hipStream_t stream) {
  const float* x   = (const float*)d_in[0];
  const float* Wx0 = (const float*)d_in[1];
  const float* Wh0 = (const float*)d_in[2];
  const float* b0  = (const float*)d_in[3];
  const float* Wx1 = (const float*)d_in[4];
  const float* Wh1 = (const float*)d_in[5];
  const float* b1  = (const float*)d_in[6];
  float* out = (float*)d_out;
  char* ws = (char*)d_ws;

  unsigned short* xb   = (unsigned short*)(ws);                  // 67,108,864 B
  unsigned short* h1   = (unsigned short*)(ws + 67108864);       // 67,108,864 B
  unsigned short* WxT0 = (unsigned short*)(ws + 134217728);      // 8,388,608 B each
  unsigned short* WhT0 = (unsigned short*)(ws + 142606336);
  unsigned short* WxT1 = (unsigned short*)(ws + 150994944);
  unsigned short* WhT1 = (unsigned short*)(ws + 159383552);
  unsigned short* ring = (unsigned short*)(ws + 167772160);      // 262,144 B
  unsigned* bars       = (unsigned*)(ws + 168034304);            // 512 B

  hipMemsetAsync(bars, 0, 512, stream);
  k_castx<<<32768, 256, 0, stream>>>(x, xb);
  k_wtrans<<<4096, 256, 0, stream>>>(Wx0, WxT0);
  k_wtrans<<<4096, 256, 0, stream>>>(Wh0, WhT0);
  k_wtrans<<<4096, 256, 0, stream>>>(Wx1, WxT1);
  k_wtrans<<<4096, 256, 0, stream>>>(Wh1, WhT1);
  // layer 0: h ring == layer-1 input buffer (mod 512 -> slot t)
  k_scan<<<NBLK, 256, 0, stream>>>(xb, WxT0, WhT0, b0, h1, 512, nullptr, bars + 0);
  // layer 1: 2-slot ring + final f32 output
  k_scan<<<NBLK, 256, 0, stream>>>(h1, WxT1, WhT1, b1, ring, 2, out, bars + 64);
}

// Round 2
// 12880.568 us; speedup vs baseline: 1.5562x; 1.5562x over previous
//
#include <hip/hip_runtime.h>
#include <hip/hip_bf16.h>

#define SEQ  512
#define HID  1024
#define G4   4096
#define NBLK 128

typedef short bf16x8 __attribute__((ext_vector_type(8)));
typedef float f32x4  __attribute__((ext_vector_type(4)));
typedef unsigned long long u64;

static __device__ __forceinline__ unsigned short f2b(float f) {
  union { float f; unsigned u; } v; v.f = f;
  unsigned r = (v.u + 0x7FFFu + ((v.u >> 16) & 1u)) >> 16;  // RNE
  return (unsigned short)r;
}

// x (B,S,I) f32 -> xb row-major (S*B, I) bf16, row r = s*64+b
__global__ __launch_bounds__(256) void k_castx(const float* __restrict__ x,
                                               unsigned short* __restrict__ xb) {
  int idx = blockIdx.x * 256 + threadIdx.x;
  int r = idx >> 8, kq = idx & 255;
  int b = r & 63, s = r >> 6;
  float4 v = *reinterpret_cast<const float4*>(x + ((size_t)b * SEQ + s) * HID + (size_t)kq * 4);
  ushort4 o;
  o.x = f2b(v.x); o.y = f2b(v.y); o.z = f2b(v.z); o.w = f2b(v.w);
  *reinterpret_cast<ushort4*>(xb + (size_t)r * HID + kq * 4) = o;
}

// W (K=1024, N=4096) f32 -> WT (N=4096, K=1024) bf16
__global__ __launch_bounds__(256) void k_wtrans(const float* __restrict__ W,
                                                unsigned short* __restrict__ WT) {
  __shared__ float tls[32][33];
  int tile = blockIdx.x;
  int nt = tile & 127, kt = tile >> 7;
  int tx = threadIdx.x & 31, ty = threadIdx.x >> 5;
  int k0 = kt * 32, n0 = nt * 32;
  for (int i = 0; i < 4; ++i)
    tls[ty + 8 * i][tx] = W[(size_t)(k0 + ty + 8 * i) * G4 + n0 + tx];
  __syncthreads();
  for (int i = 0; i < 4; ++i)
    WT[(size_t)(n0 + ty + 8 * i) * HID + k0 + tx] = f2b(tls[tx][ty + 8 * i]);
}

// Persistent fused LSTM layer scan, wave-specialized:
//   waves 0-3: x-projection for step t+1 (not on recurrence critical path)
//   waves 4-7: h @ Wh for step t + gates + state update + h broadcast
// h exchange: relaxed agent-scope (sc1) atomics, no cache-wide fences.
__global__ __launch_bounds__(512, 1) void k_scan(
    const unsigned short* __restrict__ aseq,
    const unsigned short* __restrict__ WxT,
    const unsigned short* __restrict__ WhT,
    const float* __restrict__ bias,
    unsigned short* __restrict__ hbuf, int ring_mod,
    float* __restrict__ fout,
    unsigned* __restrict__ bar) {
  __shared__ unsigned short wlds[32 * 2048];   // 128 KB weights [c][k], swizzled
  __shared__ float g_lds[2][64][35];           // double-buffered gate accum
  __shared__ unsigned lds_arr;

  const int bk  = blockIdx.x;
  const int tid = threadIdx.x;
  const int w   = tid >> 6;
  const int l   = tid & 63;
  const int lq  = l >> 4, lr = l & 15;
  const int rt  = w & 3;          // row-tile (16 batch rows) for both roles
  const bool is_h = (w >= 4);

  unsigned* barG = bar + (bk & 7) * 32;
  unsigned* barM = bar + 256;
  unsigned* rel  = bar + 288;

  if (tid == 0) lds_arr = 0;

  // ---- one-time: stage weight slice into LDS (swizzled byte addr) ----
  {
    int c = tid >> 4, seg = tid & 15;          // c: 0..31 block gate-cols
    int gate = c >> 3, nl = c & 7;
    int gcol = gate * 1024 + bk * 8 + nl;
    const unsigned short* sx = WxT + (size_t)gcol * HID;
    const unsigned short* sh = WhT + (size_t)gcol * HID;
    for (int j = 0; j < 16; ++j) {
      int kk = seg * 128 + j * 8;              // element in [0,2048)
      const unsigned short* src = (kk < 1024) ? (sx + kk) : (sh + kk - 1024);
      uint4 v = *reinterpret_cast<const uint4*>(src);
      int db = (c * 4096 + kk * 2) ^ ((c & 7) << 4);
      *reinterpret_cast<uint4*>(reinterpret_cast<char*>(wlds) + db) = v;
    }
  }

  // MFMA B-frag addressing (validated in round 1)
  char* wbase = reinterpret_cast<char*>(wlds);
  const int csw = (lr & 7) << 4;
  const int cb0 = (lr) * 4096 + lq * 16;        // col-tile 0 linear base
  const int cb1 = (16 + lr) * 4096 + lq * 16;   // col-tile 1

  // x-wave bias (per written col ct*16+lr)
  float bias_c[2];
#pragma unroll
  for (int ct = 0; ct < 2; ++ct) {
    int col = ct * 16 + lr;
    bias_c[ct] = bias[(col >> 3) * 1024 + bk * 8 + (col & 7)];
  }

  // h-wave epilogue mapping: thread -> (batch row, 2 h-cols)
  const int eb = rt * 16 + (l >> 2);
  const int np = l & 3;
  const int hcol = bk * 8 + 2 * np;
  float cA = 0.f, cB = 0.f;

  __syncthreads();
  if (is_h) __builtin_amdgcn_s_setprio(1);

  // ---- prologue: x-part of step 0 ----
  if (!is_h) {
    const unsigned short* ax = aseq + (size_t)(rt * 16 + lr) * HID + lq * 8;
    f32x4 acc[2][2] = {};
#pragma unroll 8
    for (int ks = 0; ks < 32; ++ks) {
      bf16x8 a  = *reinterpret_cast<const bf16x8*>(ax + ks * 32);
      bf16x8 b0 = *reinterpret_cast<const bf16x8*>(wbase + ((cb0 + ks * 64) ^ csw));
      bf16x8 b1 = *reinterpret_cast<const bf16x8*>(wbase + ((cb1 + ks * 64) ^ csw));
      acc[0][ks & 1] = __builtin_amdgcn_mfma_f32_16x16x32_bf16(a, b0, acc[0][ks & 1], 0, 0, 0);
      acc[1][ks & 1] = __builtin_amdgcn_mfma_f32_16x16x32_bf16(a, b1, acc[1][ks & 1], 0, 0, 0);
    }
#pragma unroll
    for (int ct = 0; ct < 2; ++ct) {
      f32x4 s = acc[ct][0] + acc[ct][1];
      int row = rt * 16 + lq * 4, col = ct * 16 + lr;
      g_lds[0][row + 0][col] = s.x + bias_c[ct];
      g_lds[0][row + 1][col] = s.y + bias_c[ct];
      g_lds[0][row + 2][col] = s.z + bias_c[ct];
      g_lds[0][row + 3][col] = s.w + bias_c[ct];
    }
  }
  __syncthreads();

  for (int t = 0; t < SEQ; ++t) {
    if (!is_h) {
      // ---------- x-waves: project x_{t+1} into g_lds[(t+1)&1] ----------
      if (t + 1 < SEQ) {
        const unsigned short* ax = aseq + ((size_t)(t + 1) * 64 + rt * 16 + lr) * HID + lq * 8;
        f32x4 acc[2][2] = {};
#pragma unroll 8
        for (int ks = 0; ks < 32; ++ks) {
          bf16x8 a  = *reinterpret_cast<const bf16x8*>(ax + ks * 32);
          bf16x8 b0 = *reinterpret_cast<const bf16x8*>(wbase + ((cb0 + ks * 64) ^ csw));
          bf16x8 b1 = *reinterpret_cast<const bf16x8*>(wbase + ((cb1 + ks * 64) ^ csw));
          acc[0][ks & 1] = __builtin_amdgcn_mfma_f32_16x16x32_bf16(a, b0, acc[0][ks & 1], 0, 0, 0);
          acc[1][ks & 1] = __builtin_amdgcn_mfma_f32_16x16x32_bf16(a, b1, acc[1][ks & 1], 0, 0, 0);
        }
        int bn = (t + 1) & 1;
#pragma unroll
        for (int ct = 0; ct < 2; ++ct) {
          f32x4 s = acc[ct][0] + acc[ct][1];
          int row = rt * 16 + lq * 4, col = ct * 16 + lr;
          g_lds[bn][row + 0][col] = s.x + bias_c[ct];
          g_lds[bn][row + 1][col] = s.y + bias_c[ct];
          g_lds[bn][row + 2][col] = s.z + bias_c[ct];
          g_lds[bn][row + 3][col] = s.w + bias_c[ct];
        }
      }
    } else {
      // ---------- h-waves: critical path ----------
      if (t > 0) {
        // wait for h[t-1] release
        long sp = 0;
        while (__hip_atomic_load(rel, __ATOMIC_RELAXED, __HIP_MEMORY_SCOPE_AGENT) < (unsigned)t) {
          if (++sp > 60000000L) break;   // bailout: wrong beats hung
          __builtin_amdgcn_s_sleep(1);
        }
        asm volatile("" ::: "memory");

        const u64* hp = reinterpret_cast<const u64*>(
            hbuf + (size_t)((t - 1) % ring_mod) * (64 * HID) + (size_t)(rt * 16 + lr) * HID) + lq * 2;
        f32x4 acc[2][2] = {};
#pragma unroll 8
        for (int ks = 0; ks < 32; ++ks) {
          u64 q0 = __hip_atomic_load(hp + ks * 8,     __ATOMIC_RELAXED, __HIP_MEMORY_SCOPE_AGENT);
          u64 q1 = __hip_atomic_load(hp + ks * 8 + 1, __ATOMIC_RELAXED, __HIP_MEMORY_SCOPE_AGENT);
          union { u64 q[2]; bf16x8 v; } u; u.q[0] = q0; u.q[1] = q1;
          bf16x8 b0 = *reinterpret_cast<const bf16x8*>(wbase + ((cb0 + 2048 + ks * 64) ^ csw));
          bf16x8 b1 = *reinterpret_cast<const bf16x8*>(wbase + ((cb1 + 2048 + ks * 64) ^ csw));
          acc[0][ks & 1] = __builtin_amdgcn_mfma_f32_16x16x32_bf16(u.v, b0, acc[0][ks & 1], 0, 0, 0);
          acc[1][ks & 1] = __builtin_amdgcn_mfma_f32_16x16x32_bf16(u.v, b1, acc[1][ks & 1], 0, 0, 0);
        }
        int bn = t & 1;
#pragma unroll
        for (int ct = 0; ct < 2; ++ct) {
          f32x4 s = acc[ct][0] + acc[ct][1];
          int row = rt * 16 + lq * 4, col = ct * 16 + lr;
          g_lds[bn][row + 0][col] += s.x;
          g_lds[bn][row + 1][col] += s.y;
          g_lds[bn][row + 2][col] += s.z;
          g_lds[bn][row + 3][col] += s.w;
        }
      }

      // epilogue: this wave's 16 rows x its 2 h-cols per lane
      {
        int bn = t & 1;
        float hv[2];
#pragma unroll
        for (int cv = 0; cv < 2; ++cv) {
          int c = 2 * np + cv;
          float gi = g_lds[bn][eb][c];
          float gf = g_lds[bn][eb][8 + c];
          float gg = g_lds[bn][eb][16 + c];
          float go = g_lds[bn][eb][24 + c];
          float ig = 1.f / (1.f + __expf(-gi));
          float fg = 1.f / (1.f + __expf(-gf));
          float e2 = __expf(2.f * gg);
          float gv = (e2 - 1.f) / (e2 + 1.f);
          float og = 1.f / (1.f + __expf(-go));
          float& cst = cv ? cB : cA;
          cst = fg * cst + ig * gv;
          float e2c = __expf(2.f * cst);
          hv[cv] = og * (e2c - 1.f) / (e2c + 1.f);
        }
        unsigned packed = (unsigned)f2b(hv[0]) | ((unsigned)f2b(hv[1]) << 16);
        unsigned* hw = reinterpret_cast<unsigned*>(
            hbuf + (size_t)(t % ring_mod) * (64 * HID) + (size_t)eb * HID + hcol);
        __hip_atomic_store(hw, packed, __ATOMIC_RELAXED, __HIP_MEMORY_SCOPE_AGENT);
        if (fout)
          *reinterpret_cast<float2*>(fout + (size_t)eb * (SEQ * HID) + (size_t)t * HID + hcol) =
              make_float2(hv[0], hv[1]);
      }

      // drain stores to coherence point, then hierarchical arrival
      asm volatile("s_waitcnt vmcnt(0)" ::: "memory");
      if (t < SEQ - 1 && l == 0) {
        unsigned pb = atomicAdd(&lds_arr, 1u);
        if ((pb & 3) == 3) {                     // last h-wave of this block
          unsigned pg = __hip_atomic_fetch_add(barG, 1u, __ATOMIC_RELAXED, __HIP_MEMORY_SCOPE_AGENT);
          if ((pg & 15) == 15) {                 // last block of 16-block group
            unsigned pm = __hip_atomic_fetch_add(barM, 1u, __ATOMIC_RELAXED, __HIP_MEMORY_SCOPE_AGENT);
            if ((pm & 7) == 7)                   // last group
              __hip_atomic_store(rel, (unsigned)(t + 1), __ATOMIC_RELAXED, __HIP_MEMORY_SCOPE_AGENT);
          }
        }
      }
    }
    __syncthreads();
  }
}

extern "C" void kernel_launch(void* const* d_in, const int* in_sizes, int n_in,
                              void* d_out, int out_size, void* d_ws, size_t ws_size,
                              hipStream_t stream) {
  const float* x   = (const float*)d_in[0];
  const float* Wx0 = (const float*)d_in[1];
  const float* Wh0 = (const float*)d_in[2];
  const float* b0  = (const float*)d_in[3];
  const float* Wx1 = (const float*)d_in[4];
  const float* Wh1 = (const float*)d_in[5];
  const float* b1  = (const float*)d_in[6];
  float* out = (float*)d_out;
  char* ws = (char*)d_ws;

  unsigned short* xb   = (unsigned short*)(ws);                  // 64 MB
  unsigned short* h1   = (unsigned short*)(ws + 67108864);       // 64 MB
  unsigned short* WxT0 = (unsigned short*)(ws + 134217728);
  unsigned short* WhT0 = (unsigned short*)(ws + 142606336);
  unsigned short* WxT1 = (unsigned short*)(ws + 150994944);
  unsigned short* WhT1 = (unsigned short*)(ws + 159383552);
  unsigned short* ring = (unsigned short*)(ws + 167772160);      // 256 KB
  unsigned* bars       = (unsigned*)(ws + 168034304);            // 4 KB

  hipMemsetAsync(bars, 0, 4096, stream);
  k_castx<<<32768, 256, 0, stream>>>(x, xb);
  k_wtrans<<<4096, 256, 0, stream>>>(Wx0, WxT0);
  k_wtrans<<<4096, 256, 0, stream>>>(Wh0, WhT0);
  k_wtrans<<<4096, 256, 0, stream>>>(Wx1, WxT1);
  k_wtrans<<<4096, 256, 0, stream>>>(Wh1, WhT1);
  // layer 0: h ring == layer-1 input buffer (slot t)
  k_scan<<<NBLK, 512, 0, stream>>>(xb, WxT0, WhT0, b0, h1, 512, nullptr, bars);
  // layer 1: 2-slot ring + final f32 output
  k_scan<<<NBLK, 512, 0, stream>>>(h1, WxT1, WhT1, b1, ring, 2, out, bars + 512);
}

// Round 3
// 5439.907 us; speedup vs baseline: 3.6848x; 2.3678x over previous
//
#include <hip/hip_runtime.h>
#include <hip/hip_bf16.h>

#define SEQ  512
#define HID  1024
#define G4   4096
#define NBLK 128   // blocks per layer; grid = 256

typedef short bf16x8 __attribute__((ext_vector_type(8)));
typedef float f32x4  __attribute__((ext_vector_type(4)));
typedef unsigned long long u64;

static __device__ __forceinline__ unsigned short f2b(float f) {
  union { float f; unsigned u; } v; v.f = f;
  unsigned r = (v.u + 0x7FFFu + ((v.u >> 16) & 1u)) >> 16;  // RNE
  return (unsigned short)r;
}

// x (B,S,I) f32 -> xb row-major (S*B, I) bf16, row r = s*64+b
__global__ __launch_bounds__(256) void k_castx(const float* __restrict__ x,
                                               unsigned short* __restrict__ xb) {
  int idx = blockIdx.x * 256 + threadIdx.x;
  int r = idx >> 8, kq = idx & 255;
  int b = r & 63, s = r >> 6;
  float4 v = *reinterpret_cast<const float4*>(x + ((size_t)b * SEQ + s) * HID + (size_t)kq * 4);
  ushort4 o;
  o.x = f2b(v.x); o.y = f2b(v.y); o.z = f2b(v.z); o.w = f2b(v.w);
  *reinterpret_cast<ushort4*>(xb + (size_t)r * HID + kq * 4) = o;
}

// W (K=1024, N=4096) f32 -> WT (N=4096, K=1024) bf16
__global__ __launch_bounds__(256) void k_wtrans(const float* __restrict__ W,
                                                unsigned short* __restrict__ WT) {
  __shared__ float tls[32][33];
  int tile = blockIdx.x;
  int nt = tile & 127, kt = tile >> 7;
  int tx = threadIdx.x & 31, ty = threadIdx.x >> 5;
  int k0 = kt * 32, n0 = nt * 32;
  for (int i = 0; i < 4; ++i)
    tls[ty + 8 * i][tx] = W[(size_t)(k0 + ty + 8 * i) * G4 + n0 + tx];
  __syncthreads();
  for (int i = 0; i < 4; ++i)
    WT[(size_t)(n0 + ty + 8 * i) * HID + k0 + tx] = f2b(tls[tx][ty + 8 * i]);
}

static __device__ __forceinline__ void wait_ge(unsigned* p, unsigned tgt) {
  long sp = 0;
  while (__hip_atomic_load(p, __ATOMIC_RELAXED, __HIP_MEMORY_SCOPE_AGENT) < tgt) {
    if (++sp > 8000000L) break;   // bailout: wrong answer beats a hang
    __builtin_amdgcn_s_sleep(1);
  }
  asm volatile("" ::: "memory");
}

// Both LSTM layers in one persistent launch, software-pipelined.
// Blocks 0..127 = layer 0, 128..255 = layer 1 (lags layer 0 by ~1.5 steps).
// Per block: waves 0-3 project the NEXT step's input (off critical path),
// waves 4-7 run the h-recurrence. Weights stay in LDS for the whole scan.
// h rings are write-once per address per launch -> plain cached loads are
// safe after the release counter is observed (dispatch acquire invalidated L2).
__global__ __launch_bounds__(512, 1) void k_scan2(
    const unsigned short* __restrict__ xb,
    const unsigned short* __restrict__ WxT0, const unsigned short* __restrict__ WhT0,
    const float* __restrict__ b0,
    const unsigned short* __restrict__ WxT1, const unsigned short* __restrict__ WhT1,
    const float* __restrict__ b1,
    unsigned short* __restrict__ h1,      // 512-slot ring (layer0 out / layer1 in)
    unsigned short* __restrict__ h2, int h2mod,  // layer1 h ring (512 if ws allows, else 4)
    float* __restrict__ out,
    unsigned* __restrict__ bars) {
  __shared__ unsigned short wlds[32 * 2048];   // 128 KB weights [c][k], swizzled
  __shared__ float g_lds[2][64][35];           // double-buffered gate accum
  __shared__ unsigned lds_arr;

  const int bk  = blockIdx.x;
  const int layer = bk >> 7;
  const int nb  = bk & 127;
  const int tid = threadIdx.x;
  const int w   = tid >> 6;
  const int l   = tid & 63;
  const int lq  = l >> 4, lr = l & 15;
  const int rt  = w & 3;
  const bool is_h = (w >= 4);

  const unsigned short* WxT = layer ? WxT1 : WxT0;
  const unsigned short* WhT = layer ? WhT1 : WhT0;
  const float* bias = layer ? b1 : b0;
  const unsigned short* aseq = layer ? h1 : xb;   // input rows (row-major (S*64,1024))
  unsigned short* hout = layer ? h2 : h1;
  const int hmod = layer ? h2mod : 512;
  float* fout = layer ? out : nullptr;
  unsigned* ownc = bars + layer * 32;   // 128B apart
  unsigned* l0c  = bars;

  if (tid == 0) lds_arr = 0;

  // ---- one-time: stage weight slice into LDS (swizzled byte addr) ----
  {
    int c = tid >> 4, seg = tid & 15;
    int gate = c >> 3, nl = c & 7;
    int gcol = gate * 1024 + nb * 8 + nl;
    const unsigned short* sx = WxT + (size_t)gcol * HID;
    const unsigned short* sh = WhT + (size_t)gcol * HID;
    for (int j = 0; j < 16; ++j) {
      int kk = seg * 128 + j * 8;
      const unsigned short* src = (kk < 1024) ? (sx + kk) : (sh + kk - 1024);
      uint4 v = *reinterpret_cast<const uint4*>(src);
      int db = (c * 4096 + kk * 2) ^ ((c & 7) << 4);
      *reinterpret_cast<uint4*>(reinterpret_cast<char*>(wlds) + db) = v;
    }
  }

  char* wbase = reinterpret_cast<char*>(wlds);
  const int csw = (lr & 7) << 4;
  const int cb0 = (lr) * 4096 + lq * 16;
  const int cb1 = (16 + lr) * 4096 + lq * 16;

  float bias_c[2];
#pragma unroll
  for (int ct = 0; ct < 2; ++ct) {
    int col = ct * 16 + lr;
    bias_c[ct] = bias[(col >> 3) * 1024 + nb * 8 + (col & 7)];
  }

  const int eb = rt * 16 + (l >> 2);
  const int np = l & 3;
  const int hcol = nb * 8 + 2 * np;
  float cA = 0.f, cB = 0.f;

  __syncthreads();
  if (is_h) __builtin_amdgcn_s_setprio(1);

  // ---- prologue: x-projection for step 0 ----
  if (!is_h) {
    if (layer) wait_ge(l0c, NBLK);                 // h1[0] ready
    const bf16x8* ax = reinterpret_cast<const bf16x8*>(aseq) + (size_t)(rt * 16 + lr) * 128 + lq;
    f32x4 acc[2][4] = {};
#pragma unroll 8
    for (int ks = 0; ks < 32; ++ks) {
      bf16x8 a  = ax[ks * 4];
      bf16x8 bb0 = *reinterpret_cast<const bf16x8*>(wbase + ((cb0 + ks * 64) ^ csw));
      bf16x8 bb1 = *reinterpret_cast<const bf16x8*>(wbase + ((cb1 + ks * 64) ^ csw));
      acc[0][ks & 3] = __builtin_amdgcn_mfma_f32_16x16x32_bf16(a, bb0, acc[0][ks & 3], 0, 0, 0);
      acc[1][ks & 3] = __builtin_amdgcn_mfma_f32_16x16x32_bf16(a, bb1, acc[1][ks & 3], 0, 0, 0);
    }
#pragma unroll
    for (int ct = 0; ct < 2; ++ct) {
      f32x4 s = (acc[ct][0] + acc[ct][1]) + (acc[ct][2] + acc[ct][3]);
      int row = rt * 16 + lq * 4, col = ct * 16 + lr;
      g_lds[0][row + 0][col] = s.x + bias_c[ct];
      g_lds[0][row + 1][col] = s.y + bias_c[ct];
      g_lds[0][row + 2][col] = s.z + bias_c[ct];
      g_lds[0][row + 3][col] = s.w + bias_c[ct];
    }
  }
  __syncthreads();

  for (int t = 0; t < SEQ; ++t) {
    if (!is_h) {
      // ---------- x-waves: project input of step t+1 ----------
      if (t + 1 < SEQ) {
        if (layer) wait_ge(l0c, (unsigned)(t + 2) * NBLK);   // h1[t+1] ready
        const bf16x8* ax = reinterpret_cast<const bf16x8*>(aseq)
                           + ((size_t)(t + 1) * 64 + rt * 16 + lr) * 128 + lq;
        f32x4 acc[2][4] = {};
#pragma unroll 8
        for (int ks = 0; ks < 32; ++ks) {
          bf16x8 a  = ax[ks * 4];
          bf16x8 bb0 = *reinterpret_cast<const bf16x8*>(wbase + ((cb0 + ks * 64) ^ csw));
          bf16x8 bb1 = *reinterpret_cast<const bf16x8*>(wbase + ((cb1 + ks * 64) ^ csw));
          acc[0][ks & 3] = __builtin_amdgcn_mfma_f32_16x16x32_bf16(a, bb0, acc[0][ks & 3], 0, 0, 0);
          acc[1][ks & 3] = __builtin_amdgcn_mfma_f32_16x16x32_bf16(a, bb1, acc[1][ks & 3], 0, 0, 0);
        }
        int bn = (t + 1) & 1;
#pragma unroll
        for (int ct = 0; ct < 2; ++ct) {
          f32x4 s = (acc[ct][0] + acc[ct][1]) + (acc[ct][2] + acc[ct][3]);
          int row = rt * 16 + lq * 4, col = ct * 16 + lr;
          g_lds[bn][row + 0][col] = s.x + bias_c[ct];
          g_lds[bn][row + 1][col] = s.y + bias_c[ct];
          g_lds[bn][row + 2][col] = s.z + bias_c[ct];
          g_lds[bn][row + 3][col] = s.w + bias_c[ct];
        }
      }
    } else {
      // ---------- h-waves: recurrence critical path ----------
      if (t > 0) {
        wait_ge(ownc, (unsigned)t * NBLK);   // all blocks of my layer finished t-1
        const size_t hbase = (size_t)((t - 1) % hmod) * (64 * HID) + (size_t)(rt * 16 + lr) * HID;
        f32x4 acc[2][4] = {};
        if (hmod != 4) {
          // write-once ring -> plain cached loads (L2-served broadcast)
          const bf16x8* hp = reinterpret_cast<const bf16x8*>(hout + hbase) + lq;
#pragma unroll 8
          for (int ks = 0; ks < 32; ++ks) {
            bf16x8 a = hp[ks * 4];
            bf16x8 bb0 = *reinterpret_cast<const bf16x8*>(wbase + ((cb0 + 2048 + ks * 64) ^ csw));
            bf16x8 bb1 = *reinterpret_cast<const bf16x8*>(wbase + ((cb1 + 2048 + ks * 64) ^ csw));
            acc[0][ks & 3] = __builtin_amdgcn_mfma_f32_16x16x32_bf16(a, bb0, acc[0][ks & 3], 0, 0, 0);
            acc[1][ks & 3] = __builtin_amdgcn_mfma_f32_16x16x32_bf16(a, bb1, acc[1][ks & 3], 0, 0, 0);
          }
        } else {
          // reused ring -> must bypass L2 (agent-scope atomic loads)
          const u64* hp = reinterpret_cast<const u64*>(hout + hbase) + lq * 2;
#pragma unroll 8
          for (int ks = 0; ks < 32; ++ks) {
            u64 q0 = __hip_atomic_load(hp + ks * 8,     __ATOMIC_RELAXED, __HIP_MEMORY_SCOPE_AGENT);
            u64 q1 = __hip_atomic_load(hp + ks * 8 + 1, __ATOMIC_RELAXED, __HIP_MEMORY_SCOPE_AGENT);
            union { u64 q[2]; bf16x8 v; } u; u.q[0] = q0; u.q[1] = q1;
            bf16x8 bb0 = *reinterpret_cast<const bf16x8*>(wbase + ((cb0 + 2048 + ks * 64) ^ csw));
            bf16x8 bb1 = *reinterpret_cast<const bf16x8*>(wbase + ((cb1 + 2048 + ks * 64) ^ csw));
            acc[0][ks & 3] = __builtin_amdgcn_mfma_f32_16x16x32_bf16(u.v, bb0, acc[0][ks & 3], 0, 0, 0);
            acc[1][ks & 3] = __builtin_amdgcn_mfma_f32_16x16x32_bf16(u.v, bb1, acc[1][ks & 3], 0, 0, 0);
          }
        }
        int bn = t & 1;
#pragma unroll
        for (int ct = 0; ct < 2; ++ct) {
          f32x4 s = (acc[ct][0] + acc[ct][1]) + (acc[ct][2] + acc[ct][3]);
          int row = rt * 16 + lq * 4, col = ct * 16 + lr;
          g_lds[bn][row + 0][col] += s.x;
          g_lds[bn][row + 1][col] += s.y;
          g_lds[bn][row + 2][col] += s.z;
          g_lds[bn][row + 3][col] += s.w;
        }
      }

      // epilogue: gates + state for 2 h-cols per lane
      {
        int bn = t & 1;
        float hv[2];
#pragma unroll
        for (int cv = 0; cv < 2; ++cv) {
          int c = 2 * np + cv;
          float gi = g_lds[bn][eb][c];
          float gf = g_lds[bn][eb][8 + c];
          float gg = g_lds[bn][eb][16 + c];
          float go = g_lds[bn][eb][24 + c];
          float ig = 1.f / (1.f + __expf(-gi));
          float fg = 1.f / (1.f + __expf(-gf));
          float e2 = __expf(2.f * gg);
          float gv = (e2 - 1.f) / (e2 + 1.f);
          float og = 1.f / (1.f + __expf(-go));
          float& cst = cv ? cB : cA;
          cst = fg * cst + ig * gv;
          float e2c = __expf(2.f * cst);
          hv[cv] = og * (e2c - 1.f) / (e2c + 1.f);
        }
        unsigned packed = (unsigned)f2b(hv[0]) | ((unsigned)f2b(hv[1]) << 16);
        unsigned* hw = reinterpret_cast<unsigned*>(
            hout + (size_t)(t % hmod) * (64 * HID) + (size_t)eb * HID + hcol);
        __hip_atomic_store(hw, packed, __ATOMIC_RELAXED, __HIP_MEMORY_SCOPE_AGENT);
        if (fout)
          *reinterpret_cast<float2*>(fout + (size_t)eb * (SEQ * HID) + (size_t)t * HID + hcol) =
              make_float2(hv[0], hv[1]);
      }

      // drain h stores to coherence point, then one arrival per block
      asm volatile("s_waitcnt vmcnt(0)" ::: "memory");
      if (l == 0) {
        unsigned pb = atomicAdd(&lds_arr, 1u);
        if ((pb & 3) == 3)
          __hip_atomic_fetch_add(ownc, 1u, __ATOMIC_RELAXED, __HIP_MEMORY_SCOPE_AGENT);
      }
    }
    __syncthreads();
  }
}

extern "C" void kernel_launch(void* const* d_in, const int* in_sizes, int n_in,
                              void* d_out, int out_size, void* d_ws, size_t ws_size,
                              hipStream_t stream) {
  const float* x   = (const float*)d_in[0];
  const float* Wx0 = (const float*)d_in[1];
  const float* Wh0 = (const float*)d_in[2];
  const float* b0  = (const float*)d_in[3];
  const float* Wx1 = (const float*)d_in[4];
  const float* Wh1 = (const float*)d_in[5];
  const float* b1  = (const float*)d_in[6];
  float* out = (float*)d_out;
  char* ws = (char*)d_ws;

  unsigned short* xb   = (unsigned short*)(ws);                  // 64 MB
  unsigned short* h1   = (unsigned short*)(ws + 67108864);       // 64 MB
  unsigned short* WxT0 = (unsigned short*)(ws + 134217728);      // 8 MB each
  unsigned short* WhT0 = (unsigned short*)(ws + 142606336);
  unsigned short* WxT1 = (unsigned short*)(ws + 150994944);
  unsigned short* WhT1 = (unsigned short*)(ws + 159383552);
  unsigned* bars       = (unsigned*)(ws + 167772160);            // 4 KB
  unsigned short* h2   = (unsigned short*)(ws + 167776256);
  // 512-slot h2 ring (write-once -> cacheable) if ws allows, else 4-slot + atomics
  int h2mod = (ws_size >= (size_t)167776256 + 67108864) ? 512 : 4;

  hipMemsetAsync(bars, 0, 4096, stream);
  k_castx<<<32768, 256, 0, stream>>>(x, xb);
  k_wtrans<<<4096, 256, 0, stream>>>(Wx0, WxT0);
  k_wtrans<<<4096, 256, 0, stream>>>(Wh0, WhT0);
  k_wtrans<<<4096, 256, 0, stream>>>(Wx1, WxT1);
  k_wtrans<<<4096, 256, 0, stream>>>(Wh1, WhT1);
  k_scan2<<<2 * NBLK, 512, 0, stream>>>(xb, WxT0, WhT0, b0, WxT1, WhT1, b1,
                                        h1, h2, h2mod, out, bars);
}

// Round 4
// 5080.906 us; speedup vs baseline: 3.9451x; 1.0707x over previous
//
#include <hip/hip_runtime.h>
#include <hip/hip_bf16.h>

#define SEQ  512
#define HID  1024
#define G4   4096
#define NBLK 128   // blocks per layer; grid = 256

typedef short bf16x8 __attribute__((ext_vector_type(8)));
typedef float f32x4  __attribute__((ext_vector_type(4)));
typedef unsigned long long u64;

static __device__ __forceinline__ unsigned short f2b(float f) {
  union { float f; unsigned u; } v; v.f = f;
  unsigned r = (v.u + 0x7FFFu + ((v.u >> 16) & 1u)) >> 16;  // RNE
  return (unsigned short)r;
}

// x (B,S,I) f32 -> xb row-major (S*B, I) bf16, row r = s*64+b
__global__ __launch_bounds__(256) void k_castx(const float* __restrict__ x,
                                               unsigned short* __restrict__ xb) {
  int idx = blockIdx.x * 256 + threadIdx.x;
  int r = idx >> 8, kq = idx & 255;
  int b = r & 63, s = r >> 6;
  float4 v = *reinterpret_cast<const float4*>(x + ((size_t)b * SEQ + s) * HID + (size_t)kq * 4);
  ushort4 o;
  o.x = f2b(v.x); o.y = f2b(v.y); o.z = f2b(v.z); o.w = f2b(v.w);
  *reinterpret_cast<ushort4*>(xb + (size_t)r * HID + kq * 4) = o;
}

// W (K=1024, N=4096) f32 -> WT (N=4096, K=1024) bf16
__global__ __launch_bounds__(256) void k_wtrans(const float* __restrict__ W,
                                                unsigned short* __restrict__ WT) {
  __shared__ float tls[32][33];
  int tile = blockIdx.x;
  int nt = tile & 127, kt = tile >> 7;
  int tx = threadIdx.x & 31, ty = threadIdx.x >> 5;
  int k0 = kt * 32, n0 = nt * 32;
  for (int i = 0; i < 4; ++i)
    tls[ty + 8 * i][tx] = W[(size_t)(k0 + ty + 8 * i) * G4 + n0 + tx];
  __syncthreads();
  for (int i = 0; i < 4; ++i)
    WT[(size_t)(n0 + ty + 8 * i) * HID + k0 + tx] = f2b(tls[tx][ty + 8 * i]);
}

// Wave-level wait: 8 group counters (128B apart) checked in ONE load + ballot.
static __device__ __forceinline__ void wave_wait8(unsigned* base, unsigned tgt) {
  unsigned* p = base + (threadIdx.x & 7) * 32;
  long sp = 0;
  for (;;) {
    unsigned v = __hip_atomic_load(p, __ATOMIC_RELAXED, __HIP_MEMORY_SCOPE_AGENT);
    if (__all(v >= tgt)) break;
    if (++sp > 10000000L) break;   // bailout: wrong answer beats a hang
    __builtin_amdgcn_s_sleep(1);
  }
  asm volatile("" ::: "memory");
}

static __device__ __forceinline__ void lds_wait(int* f, int tgt) {
  long sp = 0;
  while (__hip_atomic_load(f, __ATOMIC_RELAXED, __HIP_MEMORY_SCOPE_WORKGROUP) < tgt) {
    if (++sp > 200000000L) break;
    __builtin_amdgcn_s_sleep(1);
  }
  asm volatile("" ::: "memory");
}

// Both LSTM layers, one persistent launch. Blocks 0-127 layer0, 128-255 layer1.
// Waves 0-3: project next step's input (off critical path). Waves 4-7: h@Wh
// recurrence + in-register gate epilogue (shfl-exchange, no LDS roundtrip).
// Arrival: 8 group counters per layer (16 blocks each); one poller wave per
// block broadcasts readiness through an LDS flag.
__global__ __launch_bounds__(512, 1) void k_scan2(
    const unsigned short* __restrict__ xb,
    const unsigned short* __restrict__ WxT0, const unsigned short* __restrict__ WhT0,
    const float* __restrict__ b0,
    const unsigned short* __restrict__ WxT1, const unsigned short* __restrict__ WhT1,
    const float* __restrict__ b1,
    unsigned short* __restrict__ h1,
    unsigned short* __restrict__ h2, int h2mod,
    float* __restrict__ out,
    unsigned* __restrict__ bars) {
  __shared__ unsigned short wlds[32 * 2048];   // 128 KB weights [c][k], swizzled
  __shared__ float x_lds[2][4][8][64];         // x-partials in raw MFMA layout
  __shared__ unsigned lds_arr;
  __shared__ int hrdy, xrdy;

  const int bk  = blockIdx.x;
  const int layer = bk >> 7;
  const int nb  = bk & 127;
  const int tid = threadIdx.x;
  const int w   = tid >> 6;
  const int l   = tid & 63;
  const int lq  = l >> 4, lr = l & 15;
  const int rt  = w & 3;
  const bool is_h = (w >= 4);

  const unsigned short* WxT = layer ? WxT1 : WxT0;
  const unsigned short* WhT = layer ? WhT1 : WhT0;
  const float* bias = layer ? b1 : b0;
  const unsigned short* aseq = layer ? h1 : xb;
  unsigned short* hout = layer ? h2 : h1;
  const int hmod = layer ? h2mod : 512;
  float* fout = layer ? out : nullptr;
  unsigned* ownbase = bars + layer * 256;          // my layer's 8 group counters
  unsigned* grpc = ownbase + (nb >> 4) * 32;       // my group's counter

  if (tid == 0) { lds_arr = 0; hrdy = 0; xrdy = 0; }

  // ---- one-time: stage weight slice into LDS (swizzled byte addr) ----
  {
    int c = tid >> 4, seg = tid & 15;
    int gate = c >> 3, nl = c & 7;
    int gcol = gate * 1024 + nb * 8 + nl;
    const unsigned short* sx = WxT + (size_t)gcol * HID;
    const unsigned short* sh = WhT + (size_t)gcol * HID;
    for (int j = 0; j < 16; ++j) {
      int kk = seg * 128 + j * 8;
      const unsigned short* src = (kk < 1024) ? (sx + kk) : (sh + kk - 1024);
      uint4 v = *reinterpret_cast<const uint4*>(src);
      int db = (c * 4096 + kk * 2) ^ ((c & 7) << 4);
      *reinterpret_cast<uint4*>(reinterpret_cast<char*>(wlds) + db) = v;
    }
  }

  char* wbase = reinterpret_cast<char*>(wlds);
  const int csw = (lr & 7) << 4;
  const int cb0 = (lr) * 4096 + lq * 16;
  const int cb1 = (16 + lr) * 4096 + lq * 16;

  float bias_c[2];
#pragma unroll
  for (int ct = 0; ct < 2; ++ct) {
    int col = ct * 16 + lr;
    bias_c[ct] = bias[(col >> 3) * 1024 + nb * 8 + (col & 7)];
  }

  float cst[4] = {0.f, 0.f, 0.f, 0.f};   // c-state: 4 rows x 1 col per lane

  __syncthreads();
  if (is_h) __builtin_amdgcn_s_setprio(1);

  // ---- prologue: x-projection for step 0 into x_lds[0] ----
  if (!is_h) {
    if (layer) wave_wait8(bars, 16u);            // h1[0] complete
    const bf16x8* ax = reinterpret_cast<const bf16x8*>(aseq) + (size_t)(rt * 16 + lr) * 128 + lq;
    f32x4 acc[2][4] = {};
#pragma unroll 8
    for (int ks = 0; ks < 32; ++ks) {
      bf16x8 a  = ax[ks * 4];
      bf16x8 bb0 = *reinterpret_cast<const bf16x8*>(wbase + ((cb0 + ks * 64) ^ csw));
      bf16x8 bb1 = *reinterpret_cast<const bf16x8*>(wbase + ((cb1 + ks * 64) ^ csw));
      acc[0][ks & 3] = __builtin_amdgcn_mfma_f32_16x16x32_bf16(a, bb0, acc[0][ks & 3], 0, 0, 0);
      acc[1][ks & 3] = __builtin_amdgcn_mfma_f32_16x16x32_bf16(a, bb1, acc[1][ks & 3], 0, 0, 0);
    }
#pragma unroll
    for (int ct = 0; ct < 2; ++ct) {
      f32x4 s = (acc[ct][0] + acc[ct][1]) + (acc[ct][2] + acc[ct][3]);
      float bc = bias_c[ct];
      x_lds[0][w][ct * 4 + 0][l] = s.x + bc;
      x_lds[0][w][ct * 4 + 1][l] = s.y + bc;
      x_lds[0][w][ct * 4 + 2][l] = s.z + bc;
      x_lds[0][w][ct * 4 + 3][l] = s.w + bc;
    }
  }
  __syncthreads();

  for (int t = 0; t < SEQ; ++t) {
    if (!is_h) {
      // ---------- x-waves: project input of step t+1 into x_lds[(t+1)&1] ----------
      if (t + 1 < SEQ) {
        if (layer) {
          if (w == 0) {
            wave_wait8(bars, 16u * (unsigned)(t + 2));   // h1[t+1] complete
            __hip_atomic_store(&xrdy, t + 1, __ATOMIC_RELAXED, __HIP_MEMORY_SCOPE_WORKGROUP);
          } else {
            lds_wait(&xrdy, t + 1);
          }
        }
        const bf16x8* ax = reinterpret_cast<const bf16x8*>(aseq)
                           + ((size_t)(t + 1) * 64 + rt * 16 + lr) * 128 + lq;
        f32x4 acc[2][4] = {};
#pragma unroll 8
        for (int ks = 0; ks < 32; ++ks) {
          bf16x8 a  = ax[ks * 4];
          bf16x8 bb0 = *reinterpret_cast<const bf16x8*>(wbase + ((cb0 + ks * 64) ^ csw));
          bf16x8 bb1 = *reinterpret_cast<const bf16x8*>(wbase + ((cb1 + ks * 64) ^ csw));
          acc[0][ks & 3] = __builtin_amdgcn_mfma_f32_16x16x32_bf16(a, bb0, acc[0][ks & 3], 0, 0, 0);
          acc[1][ks & 3] = __builtin_amdgcn_mfma_f32_16x16x32_bf16(a, bb1, acc[1][ks & 3], 0, 0, 0);
        }
        int bn2 = (t + 1) & 1;
#pragma unroll
        for (int ct = 0; ct < 2; ++ct) {
          f32x4 s = (acc[ct][0] + acc[ct][1]) + (acc[ct][2] + acc[ct][3]);
          float bc = bias_c[ct];
          x_lds[bn2][w][ct * 4 + 0][l] = s.x + bc;
          x_lds[bn2][w][ct * 4 + 1][l] = s.y + bc;
          x_lds[bn2][w][ct * 4 + 2][l] = s.z + bc;
          x_lds[bn2][w][ct * 4 + 3][l] = s.w + bc;
        }
      }
    } else {
      // ---------- h-waves: recurrence critical path ----------
      const int bn = t & 1;
      f32x4 acc[2][4];
#pragma unroll
      for (int ct = 0; ct < 2; ++ct) {
        acc[ct][0] = f32x4{x_lds[bn][rt][ct * 4 + 0][l], x_lds[bn][rt][ct * 4 + 1][l],
                           x_lds[bn][rt][ct * 4 + 2][l], x_lds[bn][rt][ct * 4 + 3][l]};
        acc[ct][1] = f32x4{0.f, 0.f, 0.f, 0.f};
        acc[ct][2] = f32x4{0.f, 0.f, 0.f, 0.f};
        acc[ct][3] = f32x4{0.f, 0.f, 0.f, 0.f};
      }

      if (t > 0) {
        if (w == 4) {
          wave_wait8(ownbase, 16u * (unsigned)t);        // all blocks finished t-1
          __hip_atomic_store(&hrdy, t, __ATOMIC_RELAXED, __HIP_MEMORY_SCOPE_WORKGROUP);
        } else {
          lds_wait(&hrdy, t);
        }
        const size_t hbase = (size_t)((t - 1) % hmod) * (64 * HID) + (size_t)(rt * 16 + lr) * HID;
        if (hmod != 4) {
          const bf16x8* hp = reinterpret_cast<const bf16x8*>(hout + hbase) + lq;
#pragma unroll 8
          for (int ks = 0; ks < 32; ++ks) {
            bf16x8 a = hp[ks * 4];
            bf16x8 bb0 = *reinterpret_cast<const bf16x8*>(wbase + ((cb0 + 2048 + ks * 64) ^ csw));
            bf16x8 bb1 = *reinterpret_cast<const bf16x8*>(wbase + ((cb1 + 2048 + ks * 64) ^ csw));
            acc[0][ks & 3] = __builtin_amdgcn_mfma_f32_16x16x32_bf16(a, bb0, acc[0][ks & 3], 0, 0, 0);
            acc[1][ks & 3] = __builtin_amdgcn_mfma_f32_16x16x32_bf16(a, bb1, acc[1][ks & 3], 0, 0, 0);
          }
        } else {
          const u64* hp = reinterpret_cast<const u64*>(hout + hbase) + lq * 2;
#pragma unroll 8
          for (int ks = 0; ks < 32; ++ks) {
            u64 q0 = __hip_atomic_load(hp + ks * 8,     __ATOMIC_RELAXED, __HIP_MEMORY_SCOPE_AGENT);
            u64 q1 = __hip_atomic_load(hp + ks * 8 + 1, __ATOMIC_RELAXED, __HIP_MEMORY_SCOPE_AGENT);
            union { u64 q[2]; bf16x8 v; } u; u.q[0] = q0; u.q[1] = q1;
            bf16x8 bb0 = *reinterpret_cast<const bf16x8*>(wbase + ((cb0 + 2048 + ks * 64) ^ csw));
            bf16x8 bb1 = *reinterpret_cast<const bf16x8*>(wbase + ((cb1 + 2048 + ks * 64) ^ csw));
            acc[0][ks & 3] = __builtin_amdgcn_mfma_f32_16x16x32_bf16(u.v, bb0, acc[0][ks & 3], 0, 0, 0);
            acc[1][ks & 3] = __builtin_amdgcn_mfma_f32_16x16x32_bf16(u.v, bb1, acc[1][ks & 3], 0, 0, 0);
          }
        }
      }

      // ---- in-register epilogue ----
      f32x4 s0 = (acc[0][0] + acc[0][1]) + (acc[0][2] + acc[0][3]);
      f32x4 s1 = (acc[1][0] + acc[1][1]) + (acc[1][2] + acc[1][3]);
      float a0[4] = {s0.x, s0.y, s0.z, s0.w};   // tile0: i (lr<8) / f (lr>=8)
      float a1[4] = {s1.x, s1.y, s1.z, s1.w};   // tile1: g (lr<8) / o (lr>=8)
      float b0r[4], b1r[4];
#pragma unroll
      for (int r = 0; r < 4; ++r) {
        b0r[r] = __shfl_xor(a0[r], 8, 64);
        b1r[r] = __shfl_xor(a1[r], 8, 64);
      }
      const bool isX = ((l & 8) == 0);
      float hvf[4];
#pragma unroll
      for (int r = 0; r < 4; ++r) {
        float gi = isX ? a0[r] : b0r[r];
        float gf = isX ? b0r[r] : a0[r];
        float gg = isX ? a1[r] : b1r[r];
        float go = isX ? b1r[r] : a1[r];
        float ig = 1.f / (1.f + __expf(-gi));
        float fg = 1.f / (1.f + __expf(-gf));
        float e2 = __expf(2.f * gg);
        float gv = (e2 - 1.f) / (e2 + 1.f);
        float og = 1.f / (1.f + __expf(-go));
        cst[r] = fg * cst[r] + ig * gv;
        float e2c = __expf(2.f * cst[r]);
        hvf[r] = og * (e2c - 1.f) / (e2c + 1.f);
      }
      // col-pair packing: lane^1 exchange, then one u32 store per lane
      float hn[4];
#pragma unroll
      for (int r = 0; r < 4; ++r) hn[r] = __shfl_xor(hvf[r], 1, 64);
      const bool ev = ((l & 1) == 0);
      unsigned pk[4]; float he[4], ho[4];
#pragma unroll
      for (int r = 0; r < 4; ++r) {
        he[r] = ev ? hvf[r] : hn[r];
        ho[r] = ev ? hn[r] : hvf[r];
        pk[r] = (unsigned)f2b(he[r]) | ((unsigned)f2b(ho[r]) << 16);
      }
      const int sub = ((l >> 3) & 1) * 2 + (l & 1);     // 0..3: which row I store
      unsigned pks = sub == 0 ? pk[0] : sub == 1 ? pk[1] : sub == 2 ? pk[2] : pk[3];
      const int row = rt * 16 + lq * 4 + sub;
      const int cp  = (lr & 7) >> 1;
      unsigned* hw = reinterpret_cast<unsigned*>(hout + (size_t)(t % hmod) * (64 * HID))
                     + (size_t)row * 512 + nb * 4 + cp;
      __hip_atomic_store(hw, pks, __ATOMIC_RELAXED, __HIP_MEMORY_SCOPE_AGENT);
      if (fout) {
        float hes = sub == 0 ? he[0] : sub == 1 ? he[1] : sub == 2 ? he[2] : he[3];
        float hos = sub == 0 ? ho[0] : sub == 1 ? ho[1] : sub == 2 ? ho[2] : ho[3];
        *reinterpret_cast<float2*>(fout + (size_t)row * (SEQ * HID) + (size_t)t * HID
                                   + nb * 8 + cp * 2) = make_float2(hes, hos);
      }

      // drain h stores, then one group-arrival per block
      asm volatile("s_waitcnt vmcnt(0)" ::: "memory");
      if (l == 0) {
        unsigned pb = atomicAdd(&lds_arr, 1u);
        if ((pb & 3) == 3)
          __hip_atomic_fetch_add(grpc, 1u, __ATOMIC_RELAXED, __HIP_MEMORY_SCOPE_AGENT);
      }
    }
    __syncthreads();
  }
}

extern "C" void kernel_launch(void* const* d_in, const int* in_sizes, int n_in,
                              void* d_out, int out_size, void* d_ws, size_t ws_size,
                              hipStream_t stream) {
  const float* x   = (const float*)d_in[0];
  const float* Wx0 = (const float*)d_in[1];
  const float* Wh0 = (const float*)d_in[2];
  const float* b0  = (const float*)d_in[3];
  const float* Wx1 = (const float*)d_in[4];
  const float* Wh1 = (const float*)d_in[5];
  const float* b1  = (const float*)d_in[6];
  float* out = (float*)d_out;
  char* ws = (char*)d_ws;

  unsigned short* xb   = (unsigned short*)(ws);                  // 64 MB
  unsigned short* h1   = (unsigned short*)(ws + 67108864);       // 64 MB
  unsigned short* WxT0 = (unsigned short*)(ws + 134217728);      // 8 MB each
  unsigned short* WhT0 = (unsigned short*)(ws + 142606336);
  unsigned short* WxT1 = (unsigned short*)(ws + 150994944);
  unsigned short* WhT1 = (unsigned short*)(ws + 159383552);
  unsigned* bars       = (unsigned*)(ws + 167772160);            // 4 KB
  unsigned short* h2   = (unsigned short*)(ws + 167776256);
  int h2mod = (ws_size >= (size_t)167776256 + 67108864) ? 512 : 4;

  hipMemsetAsync(bars, 0, 4096, stream);
  k_castx<<<32768, 256, 0, stream>>>(x, xb);
  k_wtrans<<<4096, 256, 0, stream>>>(Wx0, WxT0);
  k_wtrans<<<4096, 256, 0, stream>>>(Wh0, WhT0);
  k_wtrans<<<4096, 256, 0, stream>>>(Wx1, WxT1);
  k_wtrans<<<4096, 256, 0, stream>>>(Wh1, WhT1);
  k_scan2<<<2 * NBLK, 512, 0, stream>>>(xb, WxT0, WhT0, b0, WxT1, WhT1, b1,
                                        h1, h2, h2mod, out, bars);
}

// Round 5
// 4788.306 us; speedup vs baseline: 4.1862x; 1.0611x over previous
//
#include <hip/hip_runtime.h>
#include <hip/hip_bf16.h>

#define SEQ  512
#define HID  1024
#define G4   4096
#define NBLK 128   // blocks per layer; grid = 256

typedef short bf16x8 __attribute__((ext_vector_type(8)));
typedef float f32x4  __attribute__((ext_vector_type(4)));
typedef unsigned long long u64;

static __device__ __forceinline__ unsigned short f2b(float f) {
  union { float f; unsigned u; } v; v.f = f;
  unsigned r = (v.u + 0x7FFFu + ((v.u >> 16) & 1u)) >> 16;  // RNE
  return (unsigned short)r;
}

// x (B,S,I) f32 -> xb row-major (S*B, I) bf16, row r = s*64+b
__global__ __launch_bounds__(256) void k_castx(const float* __restrict__ x,
                                               unsigned short* __restrict__ xb) {
  int idx = blockIdx.x * 256 + threadIdx.x;
  int r = idx >> 8, kq = idx & 255;
  int b = r & 63, s = r >> 6;
  float4 v = *reinterpret_cast<const float4*>(x + ((size_t)b * SEQ + s) * HID + (size_t)kq * 4);
  ushort4 o;
  o.x = f2b(v.x); o.y = f2b(v.y); o.z = f2b(v.z); o.w = f2b(v.w);
  *reinterpret_cast<ushort4*>(xb + (size_t)r * HID + kq * 4) = o;
}

// W (K=1024, N=4096) f32 -> WT (N=4096, K=1024) bf16
__global__ __launch_bounds__(256) void k_wtrans(const float* __restrict__ W,
                                                unsigned short* __restrict__ WT) {
  __shared__ float tls[32][33];
  int tile = blockIdx.x;
  int nt = tile & 127, kt = tile >> 7;
  int tx = threadIdx.x & 31, ty = threadIdx.x >> 5;
  int k0 = kt * 32, n0 = nt * 32;
  for (int i = 0; i < 4; ++i)
    tls[ty + 8 * i][tx] = W[(size_t)(k0 + ty + 8 * i) * G4 + n0 + tx];
  __syncthreads();
  for (int i = 0; i < 4; ++i)
    WT[(size_t)(n0 + ty + 8 * i) * HID + k0 + tx] = f2b(tls[tx][ty + 8 * i]);
}

// Poll 128 per-block flag words (128B apart, single-writer each, no RMW).
// Lane l checks flags for blocks l and l+64; exit when ALL >= tgt.
static __device__ __forceinline__ void poll_flags128(unsigned* flags, unsigned tgt) {
  const int l = threadIdx.x & 63;
  unsigned* p0 = flags + l * 32;
  unsigned* p1 = flags + (64 + l) * 32;
  long sp = 0;
  for (;;) {
    unsigned v0 = __hip_atomic_load(p0, __ATOMIC_RELAXED, __HIP_MEMORY_SCOPE_AGENT);
    unsigned v1 = __hip_atomic_load(p1, __ATOMIC_RELAXED, __HIP_MEMORY_SCOPE_AGENT);
    if (__all((v0 >= tgt) && (v1 >= tgt))) break;
    if (++sp > 2000000L) break;   // bailout: wrong answer beats a hang
    __builtin_amdgcn_s_sleep(1);
  }
  asm volatile("" ::: "memory");
}

static __device__ __forceinline__ void lds_wait(int* f, int tgt) {
  long sp = 0;
  while (__hip_atomic_load(f, __ATOMIC_RELAXED, __HIP_MEMORY_SCOPE_WORKGROUP) < tgt) {
    if (++sp > 50000000L) break;
    __builtin_amdgcn_s_sleep(1);
  }
  asm volatile("" ::: "memory");
}

// Both LSTM layers, one persistent launch. Blocks 0-127 layer0, 128-255 layer1.
// Waves 0-3: project next step's input (off critical path). Waves 4-7: h@Wh
// recurrence + in-register gate epilogue. Cross-block sync: per-block monotonic
// flag words (plain agent stores, no atomic RMW); one poller wave per role
// relays through an LDS flag. Output (HBM) stores issue AFTER flag publication
// so they never sit on the recurrence critical path.
__global__ __launch_bounds__(512, 1) void k_scan2(
    const unsigned short* __restrict__ xb,
    const unsigned short* __restrict__ WxT0, const unsigned short* __restrict__ WhT0,
    const float* __restrict__ b0,
    const unsigned short* __restrict__ WxT1, const unsigned short* __restrict__ WhT1,
    const float* __restrict__ b1,
    unsigned short* __restrict__ h1,
    unsigned short* __restrict__ h2, int h2mod,
    float* __restrict__ out,
    unsigned* __restrict__ bars) {
  __shared__ unsigned short wlds[32 * 2048];   // 128 KB weights [c][k], swizzled
  __shared__ float x_lds[2][4][8][64];         // x-partials in raw MFMA layout
  __shared__ unsigned lds_arr;
  __shared__ int hrdy, xrdy;

  const int bk  = blockIdx.x;
  const int layer = bk >> 7;
  const int nb  = bk & 127;
  const int tid = threadIdx.x;
  const int w   = tid >> 6;
  const int l   = tid & 63;
  const int lq  = l >> 4, lr = l & 15;
  const int rt  = w & 3;
  const bool is_h = (w >= 4);

  const unsigned short* WxT = layer ? WxT1 : WxT0;
  const unsigned short* WhT = layer ? WhT1 : WhT0;
  const float* bias = layer ? b1 : b0;
  const unsigned short* aseq = layer ? h1 : xb;
  unsigned short* hout = layer ? h2 : h1;
  const int hmod = layer ? h2mod : 512;
  float* fout = layer ? out : nullptr;
  unsigned* ownflags = bars + layer * 4096;    // my layer's 128 flag words
  unsigned* l0flags  = bars;                   // layer0 flags
  unsigned* myflag   = ownflags + nb * 32;     // this block's word (128B apart)

  if (tid == 0) { lds_arr = 0; hrdy = 0; xrdy = 0; }

  // ---- one-time: stage weight slice into LDS (swizzled byte addr) ----
  {
    int c = tid >> 4, seg = tid & 15;
    int gate = c >> 3, nl = c & 7;
    int gcol = gate * 1024 + nb * 8 + nl;
    const unsigned short* sx = WxT + (size_t)gcol * HID;
    const unsigned short* sh = WhT + (size_t)gcol * HID;
    for (int j = 0; j < 16; ++j) {
      int kk = seg * 128 + j * 8;
      const unsigned short* src = (kk < 1024) ? (sx + kk) : (sh + kk - 1024);
      uint4 v = *reinterpret_cast<const uint4*>(src);
      int db = (c * 4096 + kk * 2) ^ ((c & 7) << 4);
      *reinterpret_cast<uint4*>(reinterpret_cast<char*>(wlds) + db) = v;
    }
  }

  char* wbase = reinterpret_cast<char*>(wlds);
  const int csw = (lr & 7) << 4;
  const int cb0 = (lr) * 4096 + lq * 16;
  const int cb1 = (16 + lr) * 4096 + lq * 16;

  float bias_c[2];
#pragma unroll
  for (int ct = 0; ct < 2; ++ct) {
    int col = ct * 16 + lr;
    bias_c[ct] = bias[(col >> 3) * 1024 + nb * 8 + (col & 7)];
  }

  float cst[4] = {0.f, 0.f, 0.f, 0.f};   // c-state: 4 rows x 1 col per lane

  __syncthreads();
  if (is_h) __builtin_amdgcn_s_setprio(1);

  // ---- prologue: x-projection for step 0 into x_lds[0] ----
  if (!is_h) {
    if (layer) poll_flags128(l0flags, 1u);       // h1[0] complete
    const bf16x8* ax = reinterpret_cast<const bf16x8*>(aseq) + (size_t)(rt * 16 + lr) * 128 + lq;
    f32x4 acc[2][4] = {};
#pragma unroll 8
    for (int ks = 0; ks < 32; ++ks) {
      bf16x8 a  = ax[ks * 4];
      bf16x8 bb0 = *reinterpret_cast<const bf16x8*>(wbase + ((cb0 + ks * 64) ^ csw));
      bf16x8 bb1 = *reinterpret_cast<const bf16x8*>(wbase + ((cb1 + ks * 64) ^ csw));
      acc[0][ks & 3] = __builtin_amdgcn_mfma_f32_16x16x32_bf16(a, bb0, acc[0][ks & 3], 0, 0, 0);
      acc[1][ks & 3] = __builtin_amdgcn_mfma_f32_16x16x32_bf16(a, bb1, acc[1][ks & 3], 0, 0, 0);
    }
#pragma unroll
    for (int ct = 0; ct < 2; ++ct) {
      f32x4 s = (acc[ct][0] + acc[ct][1]) + (acc[ct][2] + acc[ct][3]);
      float bc = bias_c[ct];
      x_lds[0][w][ct * 4 + 0][l] = s.x + bc;
      x_lds[0][w][ct * 4 + 1][l] = s.y + bc;
      x_lds[0][w][ct * 4 + 2][l] = s.z + bc;
      x_lds[0][w][ct * 4 + 3][l] = s.w + bc;
    }
  }
  __syncthreads();

  for (int t = 0; t < SEQ; ++t) {
    if (!is_h) {
      // ---------- x-waves: project input of step t+1 into x_lds[(t+1)&1] ----------
      if (t + 1 < SEQ) {
        if (layer) {
          if (w == 0) {
            poll_flags128(l0flags, (unsigned)(t + 2));   // h1[t+1] complete
            __hip_atomic_store(&xrdy, t + 1, __ATOMIC_RELAXED, __HIP_MEMORY_SCOPE_WORKGROUP);
          } else {
            lds_wait(&xrdy, t + 1);
          }
        }
        const bf16x8* ax = reinterpret_cast<const bf16x8*>(aseq)
                           + ((size_t)(t + 1) * 64 + rt * 16 + lr) * 128 + lq;
        f32x4 acc[2][4] = {};
#pragma unroll 8
        for (int ks = 0; ks < 32; ++ks) {
          bf16x8 a  = ax[ks * 4];
          bf16x8 bb0 = *reinterpret_cast<const bf16x8*>(wbase + ((cb0 + ks * 64) ^ csw));
          bf16x8 bb1 = *reinterpret_cast<const bf16x8*>(wbase + ((cb1 + ks * 64) ^ csw));
          acc[0][ks & 3] = __builtin_amdgcn_mfma_f32_16x16x32_bf16(a, bb0, acc[0][ks & 3], 0, 0, 0);
          acc[1][ks & 3] = __builtin_amdgcn_mfma_f32_16x16x32_bf16(a, bb1, acc[1][ks & 3], 0, 0, 0);
        }
        int bn2 = (t + 1) & 1;
#pragma unroll
        for (int ct = 0; ct < 2; ++ct) {
          f32x4 s = (acc[ct][0] + acc[ct][1]) + (acc[ct][2] + acc[ct][3]);
          float bc = bias_c[ct];
          x_lds[bn2][w][ct * 4 + 0][l] = s.x + bc;
          x_lds[bn2][w][ct * 4 + 1][l] = s.y + bc;
          x_lds[bn2][w][ct * 4 + 2][l] = s.z + bc;
          x_lds[bn2][w][ct * 4 + 3][l] = s.w + bc;
        }
      }
    } else {
      // ---------- h-waves: recurrence critical path ----------
      const int bn = t & 1;
      f32x4 acc[2][4];
#pragma unroll
      for (int ct = 0; ct < 2; ++ct) {
        acc[ct][0] = f32x4{x_lds[bn][rt][ct * 4 + 0][l], x_lds[bn][rt][ct * 4 + 1][l],
                           x_lds[bn][rt][ct * 4 + 2][l], x_lds[bn][rt][ct * 4 + 3][l]};
        acc[ct][1] = f32x4{0.f, 0.f, 0.f, 0.f};
        acc[ct][2] = f32x4{0.f, 0.f, 0.f, 0.f};
        acc[ct][3] = f32x4{0.f, 0.f, 0.f, 0.f};
      }

      if (t > 0) {
        if (w == 4) {
          poll_flags128(ownflags, (unsigned)t);          // all blocks finished t-1
          __hip_atomic_store(&hrdy, t, __ATOMIC_RELAXED, __HIP_MEMORY_SCOPE_WORKGROUP);
        } else {
          lds_wait(&hrdy, t);
        }
        const size_t hbase = (size_t)((t - 1) % hmod) * (64 * HID) + (size_t)(rt * 16 + lr) * HID;
        if (hmod != 4) {
          const bf16x8* hp = reinterpret_cast<const bf16x8*>(hout + hbase) + lq;
#pragma unroll 8
          for (int ks = 0; ks < 32; ++ks) {
            bf16x8 a = hp[ks * 4];
            bf16x8 bb0 = *reinterpret_cast<const bf16x8*>(wbase + ((cb0 + 2048 + ks * 64) ^ csw));
            bf16x8 bb1 = *reinterpret_cast<const bf16x8*>(wbase + ((cb1 + 2048 + ks * 64) ^ csw));
            acc[0][ks & 3] = __builtin_amdgcn_mfma_f32_16x16x32_bf16(a, bb0, acc[0][ks & 3], 0, 0, 0);
            acc[1][ks & 3] = __builtin_amdgcn_mfma_f32_16x16x32_bf16(a, bb1, acc[1][ks & 3], 0, 0, 0);
          }
        } else {
          const u64* hp = reinterpret_cast<const u64*>(hout + hbase) + lq * 2;
#pragma unroll 8
          for (int ks = 0; ks < 32; ++ks) {
            u64 q0 = __hip_atomic_load(hp + ks * 8,     __ATOMIC_RELAXED, __HIP_MEMORY_SCOPE_AGENT);
            u64 q1 = __hip_atomic_load(hp + ks * 8 + 1, __ATOMIC_RELAXED, __HIP_MEMORY_SCOPE_AGENT);
            union { u64 q[2]; bf16x8 v; } u; u.q[0] = q0; u.q[1] = q1;
            bf16x8 bb0 = *reinterpret_cast<const bf16x8*>(wbase + ((cb0 + 2048 + ks * 64) ^ csw));
            bf16x8 bb1 = *reinterpret_cast<const bf16x8*>(wbase + ((cb1 + 2048 + ks * 64) ^ csw));
            acc[0][ks & 3] = __builtin_amdgcn_mfma_f32_16x16x32_bf16(u.v, bb0, acc[0][ks & 3], 0, 0, 0);
            acc[1][ks & 3] = __builtin_amdgcn_mfma_f32_16x16x32_bf16(u.v, bb1, acc[1][ks & 3], 0, 0, 0);
          }
        }
      }

      // ---- in-register epilogue ----
      f32x4 s0 = (acc[0][0] + acc[0][1]) + (acc[0][2] + acc[0][3]);
      f32x4 s1 = (acc[1][0] + acc[1][1]) + (acc[1][2] + acc[1][3]);
      float a0[4] = {s0.x, s0.y, s0.z, s0.w};   // tile0: i (lr<8) / f (lr>=8)
      float a1[4] = {s1.x, s1.y, s1.z, s1.w};   // tile1: g (lr<8) / o (lr>=8)
      float b0r[4], b1r[4];
#pragma unroll
      for (int r = 0; r < 4; ++r) {
        b0r[r] = __shfl_xor(a0[r], 8, 64);
        b1r[r] = __shfl_xor(a1[r], 8, 64);
      }
      const bool isX = ((l & 8) == 0);
      float hvf[4];
#pragma unroll
      for (int r = 0; r < 4; ++r) {
        float gi = isX ? a0[r] : b0r[r];
        float gf = isX ? b0r[r] : a0[r];
        float gg = isX ? a1[r] : b1r[r];
        float go = isX ? b1r[r] : a1[r];
        float ig = 1.f / (1.f + __expf(-gi));
        float fg = 1.f / (1.f + __expf(-gf));
        float e2 = __expf(2.f * gg);
        float gv = (e2 - 1.f) / (e2 + 1.f);
        float og = 1.f / (1.f + __expf(-go));
        cst[r] = fg * cst[r] + ig * gv;
        float e2c = __expf(2.f * cst[r]);
        hvf[r] = og * (e2c - 1.f) / (e2c + 1.f);
      }
      // col-pair packing: lane^1 exchange, then one u32 store per lane
      float hn[4];
#pragma unroll
      for (int r = 0; r < 4; ++r) hn[r] = __shfl_xor(hvf[r], 1, 64);
      const bool ev = ((l & 1) == 0);
      unsigned pk[4]; float he[4], ho[4];
#pragma unroll
      for (int r = 0; r < 4; ++r) {
        he[r] = ev ? hvf[r] : hn[r];
        ho[r] = ev ? hn[r] : hvf[r];
        pk[r] = (unsigned)f2b(he[r]) | ((unsigned)f2b(ho[r]) << 16);
      }
      const int sub = ((l >> 3) & 1) * 2 + (l & 1);     // 0..3: which row I store
      unsigned pks = sub == 0 ? pk[0] : sub == 1 ? pk[1] : sub == 2 ? pk[2] : pk[3];
      const int row = rt * 16 + lq * 4 + sub;
      const int cp  = (lr & 7) >> 1;
      unsigned* hw = reinterpret_cast<unsigned*>(hout + (size_t)(t % hmod) * (64 * HID))
                     + (size_t)row * 512 + nb * 4 + cp;
      __hip_atomic_store(hw, pks, __ATOMIC_RELAXED, __HIP_MEMORY_SCOPE_AGENT);

      // drain h-ring stores, then publish this block's flag (plain store, no RMW)
      asm volatile("s_waitcnt vmcnt(0)" ::: "memory");
      if (l == 0) {
        atomicAdd(&lds_arr, 1u);                 // LDS, monotonic
        if (w == 4) {
          long sp = 0;
          while (__hip_atomic_load(&lds_arr, __ATOMIC_RELAXED, __HIP_MEMORY_SCOPE_WORKGROUP)
                 < 4u * (unsigned)(t + 1)) {
            if (++sp > 50000000L) break;
            __builtin_amdgcn_s_sleep(1);
          }
          __hip_atomic_store(myflag, (unsigned)(t + 1), __ATOMIC_RELAXED, __HIP_MEMORY_SCOPE_AGENT);
        }
      }

      // HBM output stores AFTER publication: off the recurrence critical path
      if (fout) {
        float hes = sub == 0 ? he[0] : sub == 1 ? he[1] : sub == 2 ? he[2] : he[3];
        float hos = sub == 0 ? ho[0] : sub == 1 ? ho[1] : sub == 2 ? ho[2] : ho[3];
        *reinterpret_cast<float2*>(fout + (size_t)row * (SEQ * HID) + (size_t)t * HID
                                   + nb * 8 + cp * 2) = make_float2(hes, hos);
      }
    }
    __syncthreads();
  }
}

extern "C" void kernel_launch(void* const* d_in, const int* in_sizes, int n_in,
                              void* d_out, int out_size, void* d_ws, size_t ws_size,
                              hipStream_t stream) {
  const float* x   = (const float*)d_in[0];
  const float* Wx0 = (const float*)d_in[1];
  const float* Wh0 = (const float*)d_in[2];
  const float* b0  = (const float*)d_in[3];
  const float* Wx1 = (const float*)d_in[4];
  const float* Wh1 = (const float*)d_in[5];
  const float* b1  = (const float*)d_in[6];
  float* out = (float*)d_out;
  char* ws = (char*)d_ws;

  unsigned short* xb   = (unsigned short*)(ws);                  // 64 MB
  unsigned short* h1   = (unsigned short*)(ws + 67108864);       // 64 MB
  unsigned short* WxT0 = (unsigned short*)(ws + 134217728);      // 8 MB each
  unsigned short* WhT0 = (unsigned short*)(ws + 142606336);
  unsigned short* WxT1 = (unsigned short*)(ws + 150994944);
  unsigned short* WhT1 = (unsigned short*)(ws + 159383552);
  unsigned* bars       = (unsigned*)(ws + 167772160);            // 32 KB flags
  unsigned short* h2   = (unsigned short*)(ws + 167804928);
  int h2mod = (ws_size >= (size_t)167804928 + 67108864) ? 512 : 4;

  hipMemsetAsync(bars, 0, 32768, stream);
  k_castx<<<32768, 256, 0, stream>>>(x, xb);
  k_wtrans<<<4096, 256, 0, stream>>>(Wx0, WxT0);
  k_wtrans<<<4096, 256, 0, stream>>>(Wh0, WhT0);
  k_wtrans<<<4096, 256, 0, stream>>>(Wx1, WxT1);
  k_wtrans<<<4096, 256, 0, stream>>>(Wh1, WhT1);
  k_scan2<<<2 * NBLK, 512, 0, stream>>>(xb, WxT0, WhT0, b0, WxT1, WhT1, b1,
                                        h1, h2, h2mod, out, bars);
}